// Round 3
// baseline (818.961 us; speedup 1.0000x reference)
//
#include <hip/hip_runtime.h>

// SparseAutoEncoder: hypernetwork-generated per-sample MLP weights, fused.
// EN layers (rows in en_W2): (2000,200) lin @0, (200,100) tanh @400200, (100,10) lin @420300
// DE layers (rows in de_W2): (10,100) lin @0, (100,200) tanh @1100, (200,2000) lin @21300
// All hyper widths K = 64, batch B = 64. h layout: (b,k) b-major. xT layouts: (i,b) i-major.

// ---------------------------------------------------------------------------
// prep: transpose z (64x2000) -> zT (2000x64), and compute h_en, h_de (64x64)
// ---------------------------------------------------------------------------
__global__ __launch_bounds__(256) void prep_kernel(
    const float* __restrict__ z, const float* __restrict__ mu,
    const float* __restrict__ enW0, const float* __restrict__ enb0,
    const float* __restrict__ enW1, const float* __restrict__ enb1,
    const float* __restrict__ deW0, const float* __restrict__ deb0,
    const float* __restrict__ deW1, const float* __restrict__ deb1,
    float* __restrict__ zT, float* __restrict__ hen, float* __restrict__ hde)
{
    __shared__ float tile[64 * 65];
    __shared__ float h0s[4][64];
    const int bid  = blockIdx.x;
    const int lane = threadIdx.x & 63;
    const int g    = threadIdx.x >> 6;

    if (bid < 32) {
        // 64x64 tile transpose of z
        const int t0 = bid * 64;
        for (int bb = g; bb < 64; bb += 4) {
            int i = t0 + lane;
            tile[bb * 65 + lane] = (i < 2000) ? z[bb * 2000 + i] : 0.f;
        }
        __syncthreads();
        for (int ii = g; ii < 64; ii += 4) {
            int i = t0 + ii;
            if (i < 2000) zT[i * 64 + lane] = tile[lane * 65 + ii];
        }
    } else {
        // hypernetwork MLP: task = (which, b); lane = output neuron j
        const int task  = (bid - 32) * 4 + g;   // 0..127
        const int which = task >> 6;            // 0 = en, 1 = de
        const int b     = task & 63;
        const float* W0 = which ? deW0 : enW0;
        const float* b0 = which ? deb0 : enb0;
        const float* W1 = which ? deW1 : enW1;
        const float* b1 = which ? deb1 : enb1;
        float* hout     = which ? hde : hen;
        const int j = lane;
        float m0 = mu[b * 4 + 0], m1 = mu[b * 4 + 1], m2 = mu[b * 4 + 2], m3 = mu[b * 4 + 3];
        float v = tanhf(m0 * W0[j * 4 + 0] + m1 * W0[j * 4 + 1] +
                        m2 * W0[j * 4 + 2] + m3 * W0[j * 4 + 3] + b0[j]);
        h0s[g][j] = v;
        __syncthreads();
        float a = b1[j];
        const float* W1r = W1 + j * 64;
        #pragma unroll 8
        for (int k = 0; k < 64; ++k) a = fmaf(h0s[g][k], W1r[k], a);
        hout[b * 64 + j] = tanhf(a);
    }
}

// ---------------------------------------------------------------------------
// fused hyper-FC layer, 4x4 outer-product microkernel, explicitly software-
// pipelined (ring of 4 float4 W/x buffer pairs, static indices -> registers).
//   y[b,o] = act( sum_k h[b,k]*(T[b,k] + Wbias[o,k]) + sum_i x[b,i]*b2[o*NI+i]
//                 + b2[NO*NI+o] ),     T[b,k] = sum_i xT[i,b] * W2[(o*NI+i),k]
// Lane layout: kg = lane&15 -> k-quad 4*kg..+3 ; bgl = lane>>4 ;
//              wave owns b-rows [wave*16, +16); lane's b-quad = wave*16+bgl*4.
// Per row i: one float4 W load + one float4 x load + 16 FMAs. No LDS, no
// barriers, no scalar-memory in the hot loop (hipcc won't pipeline s_loads;
// each s_load batch costs a full ~900cy miss latency -- R1/R2 evidence).
// ---------------------------------------------------------------------------
template <int NI, int NO, int NSPLIT, bool TANH, bool ATOMIC>
__global__ __launch_bounds__(256, 8) void fc_kernel(
    const float* __restrict__ xT,   // NI x 64
    const float* __restrict__ h,    // 64 x 64 (b-major)
    const float* __restrict__ W2,   // layer base, (NO*NI+NO) x 64
    const float* __restrict__ b2,   // layer base, NO*NI+NO
    float* __restrict__ yT)         // NO x 64
{
    const int lane = threadIdx.x & 63;
    const int wave = threadIdx.x >> 6;
    const int kg   = lane & 15;          // k = 4*kg .. 4*kg+3
    const int bgl  = lane >> 4;          // 0..3
    const int b0   = wave * 16 + bgl * 4;

    const int o = blockIdx.x % NO;       // consecutive blocks share s -> share x chunk in L2
    const int s = blockIdx.x / NO;
    constexpr int CH = NI / NSPLIT;      // NI divisible by NSPLIT
    const int i0   = s * CH;
    const int iend = i0 + CH;

    // float4 row stride = 16 (64 floats). Lane's W quad: row*16 + kg.
    const float4* __restrict__ wq = (const float4*)(W2 + ((size_t)o * NI + i0) * 64) + kg;
    const float4* __restrict__ xq = (const float4*)(xT + (size_t)i0 * 64) + (wave * 4 + bgl);

    float acc[4][4];
    #pragma unroll
    for (int a = 0; a < 4; ++a)
        #pragma unroll
        for (int c = 0; c < 4; ++c) acc[a][c] = 0.f;

    auto fma16 = [&](const float4& w, const float4& x) {
        acc[0][0] = fmaf(x.x, w.x, acc[0][0]);
        acc[0][1] = fmaf(x.x, w.y, acc[0][1]);
        acc[0][2] = fmaf(x.x, w.z, acc[0][2]);
        acc[0][3] = fmaf(x.x, w.w, acc[0][3]);
        acc[1][0] = fmaf(x.y, w.x, acc[1][0]);
        acc[1][1] = fmaf(x.y, w.y, acc[1][1]);
        acc[1][2] = fmaf(x.y, w.z, acc[1][2]);
        acc[1][3] = fmaf(x.y, w.w, acc[1][3]);
        acc[2][0] = fmaf(x.z, w.x, acc[2][0]);
        acc[2][1] = fmaf(x.z, w.y, acc[2][1]);
        acc[2][2] = fmaf(x.z, w.z, acc[2][2]);
        acc[2][3] = fmaf(x.z, w.w, acc[2][3]);
        acc[3][0] = fmaf(x.w, w.x, acc[3][0]);
        acc[3][1] = fmaf(x.w, w.y, acc[3][1]);
        acc[3][2] = fmaf(x.w, w.z, acc[3][2]);
        acc[3][3] = fmaf(x.w, w.w, acc[3][3]);
    };

    if constexpr (CH >= 8 && (CH % 4) == 0) {
        // 4-deep explicit software pipeline; buffer indices are compile-time.
        float4 wbf[4], xbf[4];
        #pragma unroll
        for (int u = 0; u < 4; ++u) { wbf[u] = wq[u * 16]; xbf[u] = xq[u * 16]; }
        wq += 64; xq += 64;              // advance 4 rows

        constexpr int STEPS = (CH - 4) / 4;
        for (int it = 0; it < STEPS; ++it) {
            #pragma unroll
            for (int u = 0; u < 4; ++u) {
                fma16(wbf[u], xbf[u]);          // consume row it*4+u
                wbf[u] = wq[u * 16];            // prefetch row (it+1)*4+u
                xbf[u] = xq[u * 16];
            }
            wq += 64; xq += 64;
        }
        #pragma unroll
        for (int u = 0; u < 4; ++u) fma16(wbf[u], xbf[u]);   // drain last 4
    } else {
        // tiny-NI path (CH == 10): full unroll, all loads issue up front
        #pragma unroll
        for (int i = 0; i < CH; ++i) fma16(wq[i * 16], xq[i * 16]);
    }

    // bias-dot: xb[a] = sum over this block's i of x[b0+a, i] * b2[o*NI+i],
    // i interleaved across the 16 k-groups; reduced by the epilogue butterfly.
    const float* __restrict__ b2w = b2 + (size_t)o * NI;
    float xb[4] = {0.f, 0.f, 0.f, 0.f};
    constexpr int T16 = (CH + 15) / 16;
    #pragma unroll 4
    for (int t = 0; t < T16; ++t) {
        const int ib = i0 + t * 16 + kg;
        if (ib < iend) {
            const float  bv = b2w[ib];
            const float4 xv = *(const float4*)(xT + (size_t)ib * 64 + b0);
            xb[0] = fmaf(xv.x, bv, xb[0]);
            xb[1] = fmaf(xv.y, bv, xb[1]);
            xb[2] = fmaf(xv.z, bv, xb[2]);
            xb[3] = fmaf(xv.w, bv, xb[3]);
        }
    }

    // epilogue: contract with h over k, fold in hyper bias row (s==0 only)
    float4 wb = make_float4(0.f, 0.f, 0.f, 0.f);
    if (!ATOMIC || s == 0)
        wb = *(const float4*)(W2 + ((size_t)NO * NI + o) * 64 + 4 * kg);

    float out0, out1, out2, out3;
    #pragma unroll
    for (int a = 0; a < 4; ++a) {
        const float4 hv = *(const float4*)(h + (size_t)(b0 + a) * 64 + 4 * kg);
        float v = xb[a];
        v = fmaf(hv.x, acc[a][0] + wb.x, v);
        v = fmaf(hv.y, acc[a][1] + wb.y, v);
        v = fmaf(hv.z, acc[a][2] + wb.z, v);
        v = fmaf(hv.w, acc[a][3] + wb.w, v);
        // reduce over the 16 k-group lanes (bits 0..3 of lane)
        v += __shfl_xor(v, 1, 64);
        v += __shfl_xor(v, 2, 64);
        v += __shfl_xor(v, 4, 64);
        v += __shfl_xor(v, 8, 64);
        if (a == 0) out0 = v;
        else if (a == 1) out1 = v;
        else if (a == 2) out2 = v;
        else out3 = v;
    }

    if (kg < 4) {
        // lane kg writes b = b0 + kg  (branchless static select, no scratch)
        float v = out0;
        v = (kg == 1) ? out1 : v;
        v = (kg == 2) ? out2 : v;
        v = (kg == 3) ? out3 : v;
        const int b = b0 + kg;
        if (!ATOMIC || s == 0) v += b2[(size_t)NO * NI + o];
        if (TANH) v = tanhf(v);
        if (ATOMIC) atomicAdd(&yT[o * 64 + b], v);
        else        yT[o * 64 + b] = v;
    }
}

// ---------------------------------------------------------------------------
// finalize: d_out = [ z_reconst (64x2000 b-major) , x_enc (64x10 b-major) ]
// ---------------------------------------------------------------------------
__global__ __launch_bounds__(256) void final_kernel(
    const float* __restrict__ d3,   // 2000 x 64 (o-major)
    const float* __restrict__ y3,   // 10 x 64 (o-major)
    float* __restrict__ out)
{
    int t = blockIdx.x * 256 + threadIdx.x;
    if (t < 128000) {
        int b = t / 2000, oo = t - b * 2000;
        out[t] = d3[oo * 64 + b];
    } else if (t < 128640) {
        int u = t - 128000;
        int b = u / 10, oo = u - b * 10;
        out[t] = y3[oo * 64 + b];
    }
}

extern "C" void kernel_launch(void* const* d_in, const int* in_sizes, int n_in,
                              void* d_out, int out_size, void* d_ws, size_t ws_size,
                              hipStream_t stream)
{
    const float* z    = (const float*)d_in[0];
    const float* mu   = (const float*)d_in[1];
    const float* enW0 = (const float*)d_in[2];
    const float* enb0 = (const float*)d_in[3];
    const float* enW1 = (const float*)d_in[4];
    const float* enb1 = (const float*)d_in[5];
    const float* enW2 = (const float*)d_in[6];
    const float* enb2 = (const float*)d_in[7];
    const float* deW0 = (const float*)d_in[8];
    const float* deb0 = (const float*)d_in[9];
    const float* deW1 = (const float*)d_in[10];
    const float* deb1 = (const float*)d_in[11];
    const float* deW2 = (const float*)d_in[12];
    const float* deb2 = (const float*)d_in[13];

    float* ws  = (float*)d_ws;
    float* zT  = ws;                 // 2000*64
    float* hen = zT + 128000;        // 64*64
    float* hde = hen + 4096;         // 64*64
    float* y1  = hde + 4096;         // 200*64  (atomic target -> zeroed)
    float* y2  = y1 + 200 * 64;      // 100*64
    float* y3  = y2 + 100 * 64;      // 10*64   (x_enc, transposed; atomic -> zeroed)
    float* d1  = y3 + 10 * 64;       // 100*64
    float* d2  = d1 + 100 * 64;      // 200*64
    float* d3  = d2 + 200 * 64;      // 2000*64
    float* out = (float*)d_out;

    hipMemsetAsync(y1, 0, 200 * 64 * sizeof(float), stream);
    hipMemsetAsync(y3, 0, 10 * 64 * sizeof(float), stream);
    prep_kernel<<<64, 256, 0, stream>>>(z, mu, enW0, enb0, enW1, enb1,
                                        deW0, deb0, deW1, deb1, zT, hen, hde);
    // encoder
    fc_kernel<2000, 200, 10, false, true ><<<2000, 256, 0, stream>>>(zT, hen, enW2, enb2, y1);
    fc_kernel< 200, 100,  1, true,  false><<< 100, 256, 0, stream>>>(y1, hen, enW2 + (size_t)400200 * 64, enb2 + 400200, y2);
    fc_kernel< 100,  10, 10, false, true ><<< 100, 256, 0, stream>>>(y2, hen, enW2 + (size_t)420300 * 64, enb2 + 420300, y3);
    // decoder
    fc_kernel<  10, 100,  1, false, false><<< 100, 256, 0, stream>>>(y3, hde, deW2, deb2, d1);
    fc_kernel< 100, 200,  1, true,  false><<< 200, 256, 0, stream>>>(d1, hde, deW2 + (size_t)1100 * 64, deb2 + 1100, d2);
    fc_kernel< 200, 2000, 1, false, false><<<2000, 256, 0, stream>>>(d2, hde, deW2 + (size_t)21300 * 64, deb2 + 21300, d3);

    final_kernel<<<(128640 + 255) / 256, 256, 0, stream>>>(d3, y3, out);
}

// Round 4
// 357.383 us; speedup vs baseline: 2.2915x; 2.2915x over previous
//
#include <hip/hip_runtime.h>
#include <stdint.h>

// SparseAutoEncoder: hypernetwork-generated per-sample MLP weights, fused.
// EN layers (rows in en_W2): (2000,200) lin @0, (200,100) tanh @400200, (100,10) lin @420300
// DE layers (rows in de_W2): (10,100) lin @0, (100,200) tanh @1100, (200,2000) lin @21300
// All hyper widths K = 64, batch B = 64. h layout: (b,k) b-major. xT layouts: (i,b) i-major.

// ---------------------------------------------------------------------------
// prep: transpose z (64x2000) -> zT (2000x64), and compute h_en, h_de (64x64)
// ---------------------------------------------------------------------------
__global__ __launch_bounds__(256) void prep_kernel(
    const float* __restrict__ z, const float* __restrict__ mu,
    const float* __restrict__ enW0, const float* __restrict__ enb0,
    const float* __restrict__ enW1, const float* __restrict__ enb1,
    const float* __restrict__ deW0, const float* __restrict__ deb0,
    const float* __restrict__ deW1, const float* __restrict__ deb1,
    float* __restrict__ zT, float* __restrict__ hen, float* __restrict__ hde)
{
    __shared__ float tile[64 * 65];
    __shared__ float h0s[4][64];
    const int bid  = blockIdx.x;
    const int lane = threadIdx.x & 63;
    const int g    = threadIdx.x >> 6;

    if (bid < 32) {
        // 64x64 tile transpose of z
        const int t0 = bid * 64;
        for (int bb = g; bb < 64; bb += 4) {
            int i = t0 + lane;
            tile[bb * 65 + lane] = (i < 2000) ? z[bb * 2000 + i] : 0.f;
        }
        __syncthreads();
        for (int ii = g; ii < 64; ii += 4) {
            int i = t0 + ii;
            if (i < 2000) zT[i * 64 + lane] = tile[lane * 65 + ii];
        }
    } else {
        // hypernetwork MLP: task = (which, b); lane = output neuron j
        const int task  = (bid - 32) * 4 + g;   // 0..127
        const int which = task >> 6;            // 0 = en, 1 = de
        const int b     = task & 63;
        const float* W0 = which ? deW0 : enW0;
        const float* b0 = which ? deb0 : enb0;
        const float* W1 = which ? deW1 : enW1;
        const float* b1 = which ? deb1 : enb1;
        float* hout     = which ? hde : hen;
        const int j = lane;
        float m0 = mu[b * 4 + 0], m1 = mu[b * 4 + 1], m2 = mu[b * 4 + 2], m3 = mu[b * 4 + 3];
        float v = tanhf(m0 * W0[j * 4 + 0] + m1 * W0[j * 4 + 1] +
                        m2 * W0[j * 4 + 2] + m3 * W0[j * 4 + 3] + b0[j]);
        h0s[g][j] = v;
        __syncthreads();
        float a = b1[j];
        const float* W1r = W1 + j * 64;
        #pragma unroll 8
        for (int k = 0; k < 64; ++k) a = fmaf(h0s[g][k], W1r[k], a);
        hout[b * 64 + j] = tanhf(a);
    }
}

// ---------------------------------------------------------------------------
// async global -> LDS, 16 bytes per lane. Global src is per-lane; LDS dest is
// wave-uniform base + lane*16 (hardware-linear; our LDS layout is linear).
// ---------------------------------------------------------------------------
__device__ __forceinline__ void gload16(const float* g, float* l)
{
    __builtin_amdgcn_global_load_lds(
        (const __attribute__((address_space(1))) void*)g,
        (__attribute__((address_space(3))) void*)l,
        16, 0, 0);
}

// ---------------------------------------------------------------------------
// fused hyper-FC layer, 4x4 outer-product microkernel fed by a 2-phase
// global_load_lds double-buffer (T3-minimum schedule): staging loads live in
// the VMEM queue (zero VGPR cost), one vmcnt(0)+barrier per 20-row tile.
//   y[b,o] = act( sum_k h[b,k]*(T[b,k] + Wbias[o,k]) + sum_i x[b,i]*b2[o*NI+i]
//                 + b2[NO*NI+o] ),     T[b,k] = sum_i xT[i,b] * W2[(o*NI+i),k]
// Lane layout: kg = lane&15 -> k-quad 4*kg..+3 ; bgl = lane>>4 ;
//              wave owns b-rows [wave*16, +16); lane's b-quad = wave*16+bgl*4.
// Per row: 2 ds_read_b128 + 16 FMAs (32 cy). W ds_read = 2-way bank alias
// (free, m136); x ds_read = broadcast. No scalar-memory in the hot loop.
// NOTE: TANH layers must NOT be atomic-split (tanh of partial sums is wrong).
// ---------------------------------------------------------------------------
template <int NI, int NO, int NSPLIT, bool TANH, bool ATOMIC>
__global__ __launch_bounds__(256, 8) void fc_kernel(
    const float* __restrict__ xT,   // NI x 64
    const float* __restrict__ h,    // 64 x 64 (b-major)
    const float* __restrict__ W2,   // layer base, (NO*NI+NO) x 64
    const float* __restrict__ b2,   // layer base, NO*NI+NO
    float* __restrict__ yT)         // NO x 64
{
    const int lane = threadIdx.x & 63;
    const int wave = threadIdx.x >> 6;
    const int kg   = lane & 15;          // k = 4*kg .. 4*kg+3
    const int bgl  = lane >> 4;          // 0..3
    const int b0   = wave * 16 + bgl * 4;

    const int o = blockIdx.x % NO;       // consecutive blocks share s -> share x chunk in L2
    const int s = blockIdx.x / NO;
    constexpr int CH = NI / NSPLIT;      // NI divisible by NSPLIT
    const int i0   = s * CH;
    const int iend = i0 + CH;

    constexpr int  TR     = 20;                          // rows per tile (5 KB per array)
    constexpr bool STAGED = (CH >= TR) && (CH % TR == 0);
    constexpr int  NT     = STAGED ? (CH / TR) : 1;
    constexpr int  CHUNKS = TR / 4;                      // 1KB global_load_lds chunks per tile

    __shared__ float Wl[STAGED ? 2 * TR * 64 : 4];
    __shared__ float Xl[STAGED ? 2 * TR * 64 : 4];

    float acc[4][4];
    #pragma unroll
    for (int a = 0; a < 4; ++a)
        #pragma unroll
        for (int c = 0; c < 4; ++c) acc[a][c] = 0.f;

    auto fma16 = [&](const float4& w, const float4& x) {
        acc[0][0] = fmaf(x.x, w.x, acc[0][0]);
        acc[0][1] = fmaf(x.x, w.y, acc[0][1]);
        acc[0][2] = fmaf(x.x, w.z, acc[0][2]);
        acc[0][3] = fmaf(x.x, w.w, acc[0][3]);
        acc[1][0] = fmaf(x.y, w.x, acc[1][0]);
        acc[1][1] = fmaf(x.y, w.y, acc[1][1]);
        acc[1][2] = fmaf(x.y, w.z, acc[1][2]);
        acc[1][3] = fmaf(x.y, w.w, acc[1][3]);
        acc[2][0] = fmaf(x.z, w.x, acc[2][0]);
        acc[2][1] = fmaf(x.z, w.y, acc[2][1]);
        acc[2][2] = fmaf(x.z, w.z, acc[2][2]);
        acc[2][3] = fmaf(x.z, w.w, acc[2][3]);
        acc[3][0] = fmaf(x.w, w.x, acc[3][0]);
        acc[3][1] = fmaf(x.w, w.y, acc[3][1]);
        acc[3][2] = fmaf(x.w, w.z, acc[3][2]);
        acc[3][3] = fmaf(x.w, w.w, acc[3][3]);
    };

    if constexpr (STAGED) {
        const float* __restrict__ Wg = W2 + ((size_t)o * NI + i0) * 64;
        const float* __restrict__ xg = xT + (size_t)i0 * 64;

        auto STAGE = [&](int bufn, int tt) {
            const float* ws = Wg + (size_t)tt * TR * 64;
            const float* xs = xg + (size_t)tt * TR * 64;
            float* wl = &Wl[bufn * (TR * 64)];
            float* xl = &Xl[bufn * (TR * 64)];
            for (int c = wave; c < CHUNKS; c += 4) {   // 1KB per instr: 64 lanes x 16B
                gload16(ws + c * 256 + lane * 4, wl + c * 256);
                gload16(xs + c * 256 + lane * 4, xl + c * 256);
            }
        };

        STAGE(0, 0);
        __syncthreads();                 // drains vmcnt(0) before consuming buf 0

        int buf = 0;
        for (int t = 0; t < NT; ++t) {
            if (t + 1 < NT) STAGE(buf ^ 1, t + 1);   // flies during this tile's compute
            const float* wl = &Wl[buf * (TR * 64)];
            const float* xl = &Xl[buf * (TR * 64)];
            #pragma unroll
            for (int r = 0; r < TR; ++r) {
                const float4 w = *(const float4*)(wl + r * 64 + 4 * kg);
                const float4 x = *(const float4*)(xl + r * 64 + b0);
                fma16(w, x);
            }
            __syncthreads();             // implicit vmcnt(0): next buffer landed
            buf ^= 1;
        }
    } else {
        // tiny-NI path (CH == 10): full unroll, all loads issue up front
        const float4* __restrict__ wq = (const float4*)(W2 + ((size_t)o * NI + i0) * 64) + kg;
        const float4* __restrict__ xq = (const float4*)(xT + (size_t)i0 * 64) + (wave * 4 + bgl);
        #pragma unroll
        for (int i = 0; i < CH; ++i) fma16(wq[i * 16], xq[i * 16]);
    }

    // bias-dot: xb[a] = sum over this block's i of x[b0+a, i] * b2[o*NI+i],
    // i interleaved across the 16 k-groups; reduced by the epilogue butterfly.
    const float* __restrict__ b2w = b2 + (size_t)o * NI;
    float xb[4] = {0.f, 0.f, 0.f, 0.f};
    constexpr int T16 = (CH + 15) / 16;
    #pragma unroll 4
    for (int t = 0; t < T16; ++t) {
        const int ib = i0 + t * 16 + kg;
        if (ib < iend) {
            const float  bv = b2w[ib];
            const float4 xv = *(const float4*)(xT + (size_t)ib * 64 + b0);
            xb[0] = fmaf(xv.x, bv, xb[0]);
            xb[1] = fmaf(xv.y, bv, xb[1]);
            xb[2] = fmaf(xv.z, bv, xb[2]);
            xb[3] = fmaf(xv.w, bv, xb[3]);
        }
    }

    // epilogue: contract with h over k, fold in hyper bias row (s==0 only)
    float4 wb = make_float4(0.f, 0.f, 0.f, 0.f);
    if (!ATOMIC || s == 0)
        wb = *(const float4*)(W2 + ((size_t)NO * NI + o) * 64 + 4 * kg);

    float out0, out1, out2, out3;
    #pragma unroll
    for (int a = 0; a < 4; ++a) {
        const float4 hv = *(const float4*)(h + (size_t)(b0 + a) * 64 + 4 * kg);
        float v = xb[a];
        v = fmaf(hv.x, acc[a][0] + wb.x, v);
        v = fmaf(hv.y, acc[a][1] + wb.y, v);
        v = fmaf(hv.z, acc[a][2] + wb.z, v);
        v = fmaf(hv.w, acc[a][3] + wb.w, v);
        // reduce over the 16 k-group lanes (bits 0..3 of lane)
        v += __shfl_xor(v, 1, 64);
        v += __shfl_xor(v, 2, 64);
        v += __shfl_xor(v, 4, 64);
        v += __shfl_xor(v, 8, 64);
        if (a == 0) out0 = v;
        else if (a == 1) out1 = v;
        else if (a == 2) out2 = v;
        else out3 = v;
    }

    if (kg < 4) {
        // lane kg writes b = b0 + kg  (branchless static select, no scratch)
        float v = out0;
        v = (kg == 1) ? out1 : v;
        v = (kg == 2) ? out2 : v;
        v = (kg == 3) ? out3 : v;
        const int b = b0 + kg;
        if (!ATOMIC || s == 0) v += b2[(size_t)NO * NI + o];
        if (TANH) v = tanhf(v);
        if (ATOMIC) atomicAdd(&yT[o * 64 + b], v);
        else        yT[o * 64 + b] = v;
    }
}

// ---------------------------------------------------------------------------
// finalize: d_out = [ z_reconst (64x2000 b-major) , x_enc (64x10 b-major) ]
// ---------------------------------------------------------------------------
__global__ __launch_bounds__(256) void final_kernel(
    const float* __restrict__ d3,   // 2000 x 64 (o-major)
    const float* __restrict__ y3,   // 10 x 64 (o-major)
    float* __restrict__ out)
{
    int t = blockIdx.x * 256 + threadIdx.x;
    if (t < 128000) {
        int b = t / 2000, oo = t - b * 2000;
        out[t] = d3[oo * 64 + b];
    } else if (t < 128640) {
        int u = t - 128000;
        int b = u / 10, oo = u - b * 10;
        out[t] = y3[oo * 64 + b];
    }
}

extern "C" void kernel_launch(void* const* d_in, const int* in_sizes, int n_in,
                              void* d_out, int out_size, void* d_ws, size_t ws_size,
                              hipStream_t stream)
{
    const float* z    = (const float*)d_in[0];
    const float* mu   = (const float*)d_in[1];
    const float* enW0 = (const float*)d_in[2];
    const float* enb0 = (const float*)d_in[3];
    const float* enW1 = (const float*)d_in[4];
    const float* enb1 = (const float*)d_in[5];
    const float* enW2 = (const float*)d_in[6];
    const float* enb2 = (const float*)d_in[7];
    const float* deW0 = (const float*)d_in[8];
    const float* deb0 = (const float*)d_in[9];
    const float* deW1 = (const float*)d_in[10];
    const float* deb1 = (const float*)d_in[11];
    const float* deW2 = (const float*)d_in[12];
    const float* deb2 = (const float*)d_in[13];

    float* ws  = (float*)d_ws;
    float* zT  = ws;                 // 2000*64
    float* hen = zT + 128000;        // 64*64
    float* hde = hen + 4096;         // 64*64
    float* y1  = hde + 4096;         // 200*64  (atomic target -> zeroed)
    float* y2  = y1 + 200 * 64;      // 100*64
    float* y3  = y2 + 100 * 64;      // 10*64   (x_enc, transposed; atomic -> zeroed)
    float* d1  = y3 + 10 * 64;       // 100*64
    float* d2  = d1 + 100 * 64;      // 200*64
    float* d3  = d2 + 200 * 64;      // 2000*64
    float* out = (float*)d_out;

    hipMemsetAsync(y1, 0, 200 * 64 * sizeof(float), stream);
    hipMemsetAsync(y3, 0, 10 * 64 * sizeof(float), stream);
    prep_kernel<<<64, 256, 0, stream>>>(z, mu, enW0, enb0, enW1, enb1,
                                        deW0, deb0, deW1, deb1, zT, hen, hde);
    // encoder  (tanh layers must be NSPLIT=1: tanh of partial sums is wrong)
    fc_kernel<2000, 200, 10, false, true ><<<2000, 256, 0, stream>>>(zT, hen, enW2, enb2, y1);
    fc_kernel< 200, 100,  1, true,  false><<< 100, 256, 0, stream>>>(y1, hen, enW2 + (size_t)400200 * 64, enb2 + 400200, y2);
    fc_kernel< 100,  10, 10, false, true ><<< 100, 256, 0, stream>>>(y2, hen, enW2 + (size_t)420300 * 64, enb2 + 420300, y3);
    // decoder
    fc_kernel<  10, 100,  1, false, false><<< 100, 256, 0, stream>>>(y3, hde, deW2, deb2, d1);
    fc_kernel< 100, 200,  1, true,  false><<< 200, 256, 0, stream>>>(d1, hde, deW2 + (size_t)1100 * 64, deb2 + 1100, d2);
    fc_kernel< 200, 2000, 1, false, false><<<2000, 256, 0, stream>>>(d2, hde, deW2 + (size_t)21300 * 64, deb2 + 21300, d3);

    final_kernel<<<(128640 + 255) / 256, 256, 0, stream>>>(d3, y3, out);
}